// Round 1
// baseline (415.764 us; speedup 1.0000x reference)
//
#include <hip/hip_runtime.h>

#define NEG (-10000.0f)
#define START_TAG 62
#define STOP_TAG 63
#define SLEN 512
#define BATCH 512
#define NTAG 64

// one wave (64 lanes) per batch; lane j = tag j.
// E-column e[i] = exp(trans[i][j]) held in registers (64 VGPRs/lane).
// forward recursion: alpha_j <- m + log(sum_i exp(alpha_i - m) * E_ij) + f_sj
// p_i broadcast via v_readlane (compile-time lane index), 4 independent FMA chains.
__global__ __launch_bounds__(64) void crf_fwd(const float* __restrict__ feats,
                                              const int* __restrict__ tags,
                                              const float* __restrict__ mask,
                                              const float* __restrict__ trans,
                                              float* __restrict__ diff /* [BATCH] */) {
    const int b = blockIdx.x;
    const int j = threadIdx.x; // tag lane 0..63

    // ---- E column in registers + column sum (for exact analytic step 0) ----
    float e[NTAG];
    float colsum = 0.0f;
#pragma unroll
    for (int i = 0; i < NTAG; ++i) {
        e[i] = __expf(trans[i * NTAG + j]); // exp(NEG) underflows to exactly 0 - desired
        colsum += e[i];
    }
    const float tstop = trans[STOP_TAG * NTAG + j];

    // ---- step 0 (exact analytic; avoids the 1e4-spread underflow cliff) ----
    // alpha^1_j = NEG + log1p(sum_{i != START} E_ij) + f_0j   (E[START][*] == 0 in fp32)
    float f_cur = feats[(0 * BATCH + b) * NTAG + j];
    float m0 = mask[0 * BATCH + b];
    float alpha = (m0 > 0.0f) ? (NEG + log1pf(colsum) + f_cur)
                              : ((j == START_TAG) ? 0.0f : NEG);

    // ---- true-path score, s = 0 ----
    int tc = __builtin_amdgcn_readfirstlane(tags[0 * BATCH + b]);
    float em = __uint_as_float(__builtin_amdgcn_readlane(__float_as_uint(f_cur), tc));
    float trv = trans[START_TAG * NTAG + tc];
    float score = (em + trv) * m0;
    float msum = m0;
    int prev = tc;

    // prefetch s = 1
    float f_next = feats[(1 * BATCH + b) * NTAG + j];
    int tc_next = tags[1 * BATCH + b];
    float mk_next = mask[1 * BATCH + b];

    for (int s = 1; s < SLEN; ++s) {
        f_cur = f_next;
        tc = __builtin_amdgcn_readfirstlane(tc_next);
        float mk = mk_next;
        int sp = (s + 1 < SLEN) ? (s + 1) : s;
        f_next = feats[(sp * BATCH + b) * NTAG + j];
        tc_next = tags[sp * BATCH + b];
        mk_next = mask[sp * BATCH + b];

        // wave-wide max of alpha (butterfly)
        float m = alpha;
#pragma unroll
        for (int w = 32; w >= 1; w >>= 1)
            m = fmaxf(m, __shfl_xor(m, w, 64));

        float p = __expf(alpha - m); // in [0,1]

        // acc_j = sum_i p_i * E[i][j], p_i via readlane broadcast, 4 chains
        float acc0 = 0.0f, acc1 = 0.0f, acc2 = 0.0f, acc3 = 0.0f;
        unsigned pu = __float_as_uint(p);
#pragma unroll
        for (int i = 0; i < NTAG; i += 4) {
            acc0 = fmaf(__uint_as_float(__builtin_amdgcn_readlane(pu, i + 0)), e[i + 0], acc0);
            acc1 = fmaf(__uint_as_float(__builtin_amdgcn_readlane(pu, i + 1)), e[i + 1], acc1);
            acc2 = fmaf(__uint_as_float(__builtin_amdgcn_readlane(pu, i + 2)), e[i + 2], acc2);
            acc3 = fmaf(__uint_as_float(__builtin_amdgcn_readlane(pu, i + 3)), e[i + 3], acc3);
        }
        float acc = (acc0 + acc1) + (acc2 + acc3);

        float nxt = m + __logf(acc) + f_cur; // acc==0 (STOP col) -> -inf, benign
        alpha = (mk > 0.0f) ? nxt : alpha;

        // true-path score (wave-uniform scalar work)
        float emv = __uint_as_float(__builtin_amdgcn_readlane(__float_as_uint(f_cur), tc));
        float trs = trans[prev * NTAG + tc];
        score = fmaf(emv + trs, mk, score);
        msum += mk;
        prev = tc;
    }

    // score += trans[last_tag][STOP]
    int last_idx = (int)(msum + 0.5f) - 1;
    int ltag = tags[last_idx * BATCH + b];
    score += trans[ltag * NTAG + STOP_TAG];

    // log_z = logsumexp_j(alpha_j + trans[STOP][j])
    float v = alpha + tstop;
    float m2 = v;
#pragma unroll
    for (int w = 32; w >= 1; w >>= 1)
        m2 = fmaxf(m2, __shfl_xor(m2, w, 64));
    float pe = __expf(v - m2);
#pragma unroll
    for (int w = 32; w >= 1; w >>= 1)
        pe += __shfl_xor(pe, w, 64);
    float log_z = m2 + __logf(pe);

    if (j == 0) diff[b] = log_z - score;
}

__global__ __launch_bounds__(512) void crf_reduce(const float* __restrict__ diff,
                                                  float* __restrict__ out) {
    __shared__ float sdata[8];
    int t = threadIdx.x;
    float val = diff[t];
#pragma unroll
    for (int w = 32; w >= 1; w >>= 1)
        val += __shfl_xor(val, w, 64);
    if ((t & 63) == 0) sdata[t >> 6] = val;
    __syncthreads();
    if (t == 0) {
        float ssum = 0.0f;
        for (int i = 0; i < 8; ++i) ssum += sdata[i];
        out[0] = ssum * (1.0f / (float)BATCH);
    }
}

extern "C" void kernel_launch(void* const* d_in, const int* in_sizes, int n_in,
                              void* d_out, int out_size, void* d_ws, size_t ws_size,
                              hipStream_t stream) {
    const float* feats = (const float*)d_in[0];
    const int* tags = (const int*)d_in[1];
    const float* mask = (const float*)d_in[2];
    const float* trans = (const float*)d_in[3];
    float* out = (float*)d_out;
    float* diff = (float*)d_ws; // 512 floats

    crf_fwd<<<BATCH, 64, 0, stream>>>(feats, tags, mask, trans, diff);
    crf_reduce<<<1, 512, 0, stream>>>(diff, out);
}